// Round 8
// baseline (208.832 us; speedup 1.0000x reference)
//
#include <hip/hip_runtime.h>
#include <hip/hip_bf16.h>

typedef unsigned short u16;
typedef unsigned int u32;
typedef short bf16x8 __attribute__((ext_vector_type(8)));
typedef float f32x4 __attribute__((ext_vector_type(4)));
typedef float f32x16 __attribute__((ext_vector_type(16)));
typedef u16 u16x8 __attribute__((ext_vector_type(8)));

#define HID 1024
#define BATCH 4096
#define KTOT 2048       // concat K: [x | h_prev]
#define NT 32           // K tiles of 64
// LDS element-index region bases: [A buf0 | A buf1 | B buf0 | B buf1]
#define A0B 0
#define A1B 16384
#define B0B 32768
#define B1B 49152

__device__ __forceinline__ u16 f2bf(float f) {
  u32 v = __builtin_bit_cast(u32, f);
  u32 r = (v + 0x7fffu + ((v >> 16) & 1u)) >> 16;  // round-nearest-even
  return (u16)r;
}
__device__ __forceinline__ float sigmoid_fast(float x) {
  return 1.0f / (1.0f + __expf(-x));
}
__device__ __forceinline__ float tanh_fast(float x) {
  return 2.0f * sigmoid_fast(2.0f * x) - 1.0f;
}
__device__ __forceinline__ void gl_lds16(const void* g, void* l) {
  __builtin_amdgcn_global_load_lds(
      (const __attribute__((address_space(1))) u32*)g,
      (__attribute__((address_space(3))) u32*)l, 16, 0, 0);
}

// ---------------------------------------------------------------------------
// prep_all: fused prep. Blocks [0,4096) build xh (bf16 [B][2048]); blocks
// [4096,6144) build Bt[n'][k] (bf16, gate-interleaved n') via LDS transpose.
// ---------------------------------------------------------------------------
__global__ __launch_bounds__(256) void prep_all(
    const float* __restrict__ x, const float* __restrict__ hp,
    const float* __restrict__ igx, const float* __restrict__ fgx,
    const float* __restrict__ ogx, const float* __restrict__ cgx,
    const float* __restrict__ igu, const float* __restrict__ fgu,
    const float* __restrict__ ogu, const float* __restrict__ cgu,
    u16* __restrict__ xh, u16* __restrict__ bt) {
  __shared__ u16 lds[64 * 66];
  if (blockIdx.x < 4096) {
    int c = blockIdx.x * 256 + threadIdx.x;  // chunk id, 8 elems each
    int row = c >> 8;
    int col0 = (c & 255) << 3;
    const float* src = (col0 < 1024)
                           ? (x + (size_t)row * 1024 + col0)
                           : (hp + (size_t)row * 1024 + (col0 - 1024));
    f32x4 a = *(const f32x4*)(src);
    f32x4 b = *(const f32x4*)(src + 4);
    u16x8 v;
#pragma unroll
    for (int j = 0; j < 4; ++j) { v[j] = f2bf(a[j]); v[j + 4] = f2bf(b[j]); }
    *(u16x8*)(xh + (size_t)row * KTOT + col0) = v;
    return;
  }
  // ---- weight transpose: n' = (h/16)*64 + g*16 + (h%16), k = which*1024+ksrc
  const float* srcs[8] = {igx, fgx, ogx, cgx, igu, fgu, ogu, cgu};
  int bid = blockIdx.x - 4096;
  int m = bid >> 8;            // matrix 0..7
  int tile = bid & 255;        // 64x64 tile
  int th = tile & 15, tk = tile >> 4;
  int h0 = th << 6, k0 = tk << 6;
  int g = m & 3, which = m >> 2;
  const float* W = srcs[m] + (size_t)k0 * HID + h0;

  int t = threadIdx.x;
  int r1 = t >> 4;
  int c1 = (t & 15) << 2;
#pragma unroll
  for (int p = 0; p < 4; ++p) {
    int row = (p << 4) + r1;
    f32x4 v = *(const f32x4*)(W + (size_t)row * HID + c1);
    u32 p0 = (u32)f2bf(v[0]) | ((u32)f2bf(v[1]) << 16);
    u32 p1 = (u32)f2bf(v[2]) | ((u32)f2bf(v[3]) << 16);
    u32* d = (u32*)&lds[row * 66 + c1];
    d[0] = p0;
    d[1] = p1;
  }
  __syncthreads();
  int nl = t >> 2;
  int kc = t & 3;
  int row_np = ((h0 >> 4) << 6) + ((nl >> 4) << 6) + (g << 4) + (nl & 15);
  size_t dst = (size_t)row_np * KTOT + (size_t)which * 1024 + k0;
  u16x8 a2, b2;
#pragma unroll
  for (int j = 0; j < 8; ++j) {
    a2[j] = lds[(kc * 8 + j) * 66 + nl];
    b2[j] = lds[(kc * 8 + 32 + j) * 66 + nl];
  }
  *(u16x8*)(&bt[dst + kc * 8]) = a2;
  *(u16x8*)(&bt[dst + kc * 8 + 32]) = b2;
}

// ---------------------------------------------------------------------------
// lstm_gemm (R8): 256x256 tile, 8 waves (2Mx4N), BK=64, ONE barrier per
// K-tile (R6 liveness argument), stage-at-top, T1 XCD swizzle, XOR k-chunk
// swizzle via pre-swizzled global source (conflicts=0), 128 KiB LDS dbuf.
//
// R8 change: MFMA shape 16x16x32 -> 32x32x16 (higher measured pipe ceiling
// 2495 vs 2075 TF; half the MFMA instructions for identical LDS traffic:
// 24 b128 reads + 32 MFMA per wave per K-tile). Per wave: 4 m-frags x
// 2 n-frags of f32x16 acc (128 AGPRs). A-frag (m,ks): lane reads
// A[wr+m*32+(l&31)][ks*16+(l>>5)*8 ..+8]; B-frag (n,ks) symmetric.
// C layout: col=lane&31, row=(reg&3)+8*(reg>>2)+4*(lane>>5): 32-wide col
// frags put gate i/o in lanes 0-15 and f/c in lanes 16-31 (same hcol), so
// the epilogue pairs lanes l and l^16 via one-time __shfl_xor(...,16)
// (128 shuffles total) and each lane computes 8 cells per m-frag.
// Two A-frag register sets only (R4-proven no-spill budget).
// ---------------------------------------------------------------------------
__global__ __launch_bounds__(512, 2) void lstm_gemm(
    const u16* __restrict__ xh, const u16* __restrict__ bt,
    const float* __restrict__ cprev,
    const float* __restrict__ ib, const float* __restrict__ fb,
    const float* __restrict__ ob, const float* __restrict__ cb,
    float* __restrict__ hout, float* __restrict__ cout) {
  __shared__ __align__(16) u16 lds[4 * 16384];   // 128 KiB

  int sx = threadIdx.x;
  // T1: bid%8 -> XCD; XCD k owns brows [4*(k&3),+4), bcols [8*(k>>2),+8)
  int bid = blockIdx.x;
  int xcd = bid & 7, lid = bid >> 3;
  int brow = ((xcd & 3) << 2) | (lid & 3);
  int bcol = ((xcd >> 2) << 3) | (lid >> 2);

  int w = sx >> 6, l = sx & 63;
  int wr = (w >> 2) << 7;              // 0 | 128 (WARPS_M = 2)
  int wc = (w & 3) << 6;               // 0,64,128,192 (WARPS_N = 4)
  int grow = brow << 8;

  // staging source pointers (per-lane global addr carries the k-chunk swizzle)
  int prow = sx >> 3;                                    // 0..63
  int koff = ((sx & 7) ^ (prow & 7)) << 3;               // swizzled k elems
  const u16* aS0 = xh + (size_t)(grow + prow) * KTOT + koff;   // rows 0-127
  const u16* aS1 = aS0 + (size_t)128 * KTOT;                   // rows 128-255
  const u16* bS0 = bt + (size_t)(bcol * 256 + prow) * KTOT + koff;
  const u16* bS1 = bS0 + (size_t)128 * KTOT;
  int sx8 = sx * 8;

  // fragment read addressing (32x32x16): row = base + (l&31);
  // logical k-chunk (8 elems) = ks*2 + (l>>5); physical = logical ^ (row&7),
  // row&7 == l&7 (all row bases are multiples of 32).
  int l31 = l & 31, hi = l >> 5, side = (l >> 4) & 1;
  int arow_l = (wr + l31) << 6;
  int brow_l = (wc + l31) << 6;
  int pk0 = ((0 + hi) ^ (l & 7)) << 3;
  int pk1 = ((2 + hi) ^ (l & 7)) << 3;
  int pk2 = ((4 + hi) ^ (l & 7)) << 3;
  int pk3 = ((6 + hi) ^ (l & 7)) << 3;

  f32x16 acc[4][2] = {};
  bf16x8 af0[4], af1[4];      // two rotating A-frag sets (4 k-steps each)
  bf16x8 bfr[2][4];           // B frags, read once per tile

#define STG(P_, K_, D_)                                                       \
  gl_lds16((P_) + (K_), &lds[(D_) + sx8]);                                    \
  gl_lds16((P_) + (size_t)64 * KTOT + (K_), &lds[(D_) + 4096 + sx8]);

#define ISS_A(D_, AC_, M_)                                                    \
  D_[0] = *(const bf16x8*)&lds[(AC_) + arow_l + (M_) * 2048 + pk0];           \
  D_[1] = *(const bf16x8*)&lds[(AC_) + arow_l + (M_) * 2048 + pk1];           \
  D_[2] = *(const bf16x8*)&lds[(AC_) + arow_l + (M_) * 2048 + pk2];           \
  D_[3] = *(const bf16x8*)&lds[(AC_) + arow_l + (M_) * 2048 + pk3];

#define ISS_B(BC_)                                                            \
  bfr[0][0] = *(const bf16x8*)&lds[(BC_) + brow_l + pk0];                     \
  bfr[0][1] = *(const bf16x8*)&lds[(BC_) + brow_l + pk1];                     \
  bfr[0][2] = *(const bf16x8*)&lds[(BC_) + brow_l + pk2];                     \
  bfr[0][3] = *(const bf16x8*)&lds[(BC_) + brow_l + pk3];                     \
  bfr[1][0] = *(const bf16x8*)&lds[(BC_) + brow_l + 2048 + pk0];              \
  bfr[1][1] = *(const bf16x8*)&lds[(BC_) + brow_l + 2048 + pk1];              \
  bfr[1][2] = *(const bf16x8*)&lds[(BC_) + brow_l + 2048 + pk2];              \
  bfr[1][3] = *(const bf16x8*)&lds[(BC_) + brow_l + 2048 + pk3];

#define MFMA8(M_, AF_)                                                        \
  _Pragma("unroll") for (int n = 0; n < 2; ++n) {                             \
    _Pragma("unroll") for (int ks = 0; ks < 4; ++ks) {                        \
      acc[M_][n] = __builtin_amdgcn_mfma_f32_32x32x16_bf16(                   \
          AF_[ks], bfr[n][ks], acc[M_][n], 0, 0, 0);                          \
    }                                                                         \
  }

  // interior: 24 ds_reads + 32 MFMA, compiler-scheduled (partial lgkmcnt);
  // each cluster's A-reads lead by one cluster via the 2-set rotation
#define INTERIOR(AC_, BC_)                                                    \
  ISS_B((BC_))                                                                \
  ISS_A(af0, (AC_), 0)                                                        \
  ISS_A(af1, (AC_), 1)                                                        \
  MFMA8(0, af0)                                                               \
  ISS_A(af0, (AC_), 2)                                                        \
  MFMA8(1, af1)                                                               \
  ISS_A(af1, (AC_), 3)                                                        \
  MFMA8(2, af0)                                                               \
  MFMA8(3, af1)

  // full tile: stage next tile's A+B at top (max DMA flight), then interior
#define TILE(AC_, BC_, KN_, AD_, BD_)                                         \
  {                                                                           \
    STG(aS0, (KN_), (AD_))                                                    \
    STG(aS1, (KN_), (AD_) + 8192)                                             \
    STG(bS0, (KN_), (BD_))                                                    \
    STG(bS1, (KN_), (BD_) + 8192)                                             \
    __builtin_amdgcn_sched_barrier(0);                                        \
    INTERIOR(AC_, BC_)                                                        \
  }

  // prologue: tile 0's A+B; __syncthreads drains vmcnt(0) + barriers
  STG(aS0, 0, A0B)
  STG(aS1, 0, A0B + 8192)
  STG(bS0, 0, B0B)
  STG(bS1, 0, B0B + 8192)
  __syncthreads();

  // tiles 0..29: uniform bodies, stage tile t+1 into the other buffer
  for (int tp = 0; tp < 15; ++tp) {
    int k1 = (2 * tp + 1) << 6;
    int k2 = (2 * tp + 2) << 6;
    TILE(A0B, B0B, k1, A1B, B1B)
    __syncthreads();
    TILE(A1B, B1B, k2, A0B, B0B)
    __syncthreads();
  }
  // tile 30: stage tile 31; tile 31: no stage
  TILE(A0B, B0B, 31 << 6, A1B, B1B)
  __syncthreads();
  INTERIOR(A1B, B1B)

#undef TILE
#undef INTERIOR
#undef MFMA8
#undef ISS_A
#undef ISS_B
#undef STG

  // Epilogue. Lane l holds cols hcol(j5=l&31): frag n, side=(l>>4)&1 gives
  // gate 2n+side. Lane pair (l, l^16) shares hcol and the row set; lane with
  // side=0 computes regs 0..7 (rows 0-3,8-11 +4*hi), side=1 regs 8..15
  // (rows 16-19,24-27 +4*hi). __shfl_xor(...,16) supplies the partner gates.
  int hcol = ((bcol << 2) + (w & 3)) * 16 + (l31 & 15);
  float bi = ib[hcol];
  float bff = fb[hcol];
  float bo = ob[hcol];
  float bc = cb[hcol];

#pragma unroll
  for (int m = 0; m < 4; ++m) {
    int rowb = grow + wr + m * 32 + 4 * hi + (side ? 16 : 0);
#pragma unroll
    for (int rr = 0; rr < 8; ++rr) {
      float o_lo0 = acc[m][0][rr], o_hi0 = acc[m][0][rr + 8];
      float o_lo1 = acc[m][1][rr], o_hi1 = acc[m][1][rr + 8];
      float r_lo0 = __shfl_xor(o_lo0, 16, 64);
      float r_hi0 = __shfl_xor(o_hi0, 16, 64);
      float r_lo1 = __shfl_xor(o_lo1, 16, 64);
      float r_hi1 = __shfl_xor(o_hi1, 16, 64);
      float iv = side ? r_hi0 : o_lo0;   // gate i
      float fv = side ? o_hi0 : r_lo0;   // gate f
      float ov = side ? r_hi1 : o_lo1;   // gate o
      float gv = side ? o_hi1 : r_lo1;   // gate c (candidate)
      int row = rowb + (rr & 3) + 8 * (rr >> 2);
      size_t idx = (size_t)row * HID + hcol;
      float gi = sigmoid_fast(iv + bi);
      float gf = sigmoid_fast(fv + bff);
      float go = sigmoid_fast(ov + bo);
      float gc = tanh_fast(gv + bc);
      float cp = cprev[idx];
      float cv = gf * cp + gi * gc;
      hout[idx] = go * tanh_fast(cv);
      cout[idx] = cv;
    }
  }
}

extern "C" void kernel_launch(void* const* d_in, const int* in_sizes, int n_in,
                              void* d_out, int out_size, void* d_ws, size_t ws_size,
                              hipStream_t stream) {
  const float* x   = (const float*)d_in[0];
  const float* hp  = (const float*)d_in[1];
  const float* cp  = (const float*)d_in[2];
  const float* igx = (const float*)d_in[3];
  const float* igu = (const float*)d_in[4];
  const float* ib  = (const float*)d_in[5];
  const float* fgx = (const float*)d_in[6];
  const float* fgu = (const float*)d_in[7];
  const float* fb  = (const float*)d_in[8];
  const float* ogx = (const float*)d_in[9];
  const float* ogu = (const float*)d_in[10];
  const float* ob  = (const float*)d_in[11];
  const float* cgx = (const float*)d_in[12];
  const float* cgu = (const float*)d_in[13];
  const float* cb  = (const float*)d_in[14];

  u16* bt = (u16*)d_ws;                         // [4096][2048] bf16 = 16 MiB
  u16* xh = bt + (size_t)4096 * 2048;           // [4096][2048] bf16 = 16 MiB
  float* hout = (float*)d_out;
  float* cout = hout + (size_t)BATCH * HID;

  prep_all<<<6144, 256, 0, stream>>>(x, hp, igx, fgx, ogx, cgx,
                                     igu, fgu, ogu, cgu, xh, bt);
  lstm_gemm<<<256, 512, 0, stream>>>(xh, bt, cp, ib, fb, ob, cb,
                                     hout, cout);
}